// Round 1
// baseline (1134.935 us; speedup 1.0000x reference)
//
#include <hip/hip_runtime.h>

// ---- problem constants ----
#define NAGENTS   32768
#define HDIM      64
#define EDIM      16
#define IN_F      40
#define SLAB      65536          // NAGENTS*2
#define SPLIT     1310720        // 20*SLAB : flat indices below -> traj_abs, above -> out
#define PRED      30
#define LN_EPS    1e-5f

#define AGENTS_PER_BLOCK 64
#define NTHREADS  256
#define NBLOCKS   (NAGENTS / AGENTS_PER_BLOCK)   // 512

// ---- ws layout (float offsets) ----
#define WS_H      0                         // h transposed [k][b]  : 64*32768
#define WS_C      2097152                   // c transposed [k][b]
#define WS_WHT    (2*2097152)               // W_hh^T [k][j] : 64*256
#define WS_WIT    (WS_WHT + 16384)          // W_ih^T [k][j] : 16*256
#define WS_BIAS   (WS_WIT + 4096)           // b_ih + b_hh : 256
// total ~16.1 MB

__device__ __forceinline__ float fsigmoid(float x) {
    return 1.f / (1.f + __expf(-x));
}
__device__ __forceinline__ float ftanh(float x) {
    float t = __expf(-2.f * fabsf(x));
    float r = (1.f - t) / (1.f + t);
    return copysignf(r, x);
}
__device__ __forceinline__ float lrelu(float x) {
    return x > 0.f ? x : 0.01f * x;
}

__global__ void init_kernel(const float* __restrict__ dec_h,
                            const float* __restrict__ W_ih,
                            const float* __restrict__ W_hh,
                            const float* __restrict__ b_ih,
                            const float* __restrict__ b_hh,
                            float* __restrict__ ws) {
    int tid = blockIdx.x * blockDim.x + threadIdx.x;
    const int N = HDIM * NAGENTS;  // 2M
    for (int i = tid; i < N; i += gridDim.x * blockDim.x) {
        int k = i >> 15;               // i / NAGENTS
        int b = i & (NAGENTS - 1);
        ws[WS_H + i] = dec_h[b * HDIM + k];   // transpose: write coalesced
        ws[WS_C + i] = 0.f;
    }
    if (tid < 16384) {                 // W_hh^T
        int k = tid >> 8, j = tid & 255;
        ws[WS_WHT + tid] = W_hh[j * HDIM + k];
    }
    if (tid < 4096) {                  // W_ih^T
        int k = tid >> 8, j = tid & 255;
        ws[WS_WIT + tid] = W_ih[j * EDIM + k];
    }
    if (tid < 256) ws[WS_BIAS + tid] = b_ih[tid] + b_hh[tid];
}

// cst layout offsets
#define C_EMBW  0        // 640
#define C_EMBB  640      // 16
#define C_LN1G  656      // 40
#define C_LN1B  696      // 40
#define C_LN2G  736      // 64
#define C_LN2B  800      // 64
#define C_H2PW  864      // 128
#define C_H2PB  992      // 2
#define C_TOT   994

__global__ __launch_bounds__(NTHREADS, 2)
void step_kernel(int s,
                 const float* __restrict__ traj,
                 float* __restrict__ out,
                 float* __restrict__ ws,
                 const float* __restrict__ emb_W, const float* __restrict__ emb_b,
                 const float* __restrict__ h2p_W, const float* __restrict__ h2p_b,
                 const float* __restrict__ ln1_g, const float* __restrict__ ln1_b,
                 const float* __restrict__ ln2_g, const float* __restrict__ ln2_b) {
    __shared__ float row[64 * 41];     // padded (+1) traj rows, per agent
    __shared__ float xT[EDIM * 64];    // embedded input, transposed [e][a]
    __shared__ float hT[HDIM * 64];    // h, transposed [k][a]; reused for h_new
    __shared__ float cst[C_TOT];

    const int tid = threadIdx.x;
    const int a0 = blockIdx.x * AGENTS_PER_BLOCK;
    float* __restrict__ h_ws = ws + WS_H;
    float* __restrict__ c_ws = ws + WS_C;
    const float* __restrict__ WhT = ws + WS_WHT;
    const float* __restrict__ WiT = ws + WS_WIT;
    const float* __restrict__ bias = ws + WS_BIAS;

    // ---- stage small consts ----
    for (int i = tid; i < 640; i += NTHREADS) cst[C_EMBW + i] = emb_W[i];
    if (tid < 16)  cst[C_EMBB + tid] = emb_b[tid];
    if (tid < 40)  { cst[C_LN1G + tid] = ln1_g[tid]; cst[C_LN1B + tid] = ln1_b[tid]; }
    if (tid < 64)  { cst[C_LN2G + tid] = ln2_g[tid]; cst[C_LN2B + tid] = ln2_b[tid]; }
    if (tid < 128) cst[C_H2PW + tid] = h2p_W[tid];
    if (tid < 2)   cst[C_H2PB + tid] = h2p_b[tid];

    // ---- stage traj window rows (flat sliding window over traj_abs ++ out) ----
    {
        const int Gb = s * SLAB + a0 * IN_F;
        for (int g = tid; g < 64 * IN_F; g += NTHREADS) {
            int G = Gb + g;
            float v = (G < SPLIT) ? traj[G] : out[G - SPLIT];
            int a = g / IN_F;
            int f = g - a * IN_F;
            row[a * 41 + f] = v;
        }
    }
    // ---- stage h (already transposed in ws) ----
    {
        int l = tid & 63;
        int kw = (tid >> 6) * 16;
        for (int kk = 0; kk < 16; ++kk) {
            int k = kw + kk;
            hT[k * 64 + l] = h_ws[k * NAGENTS + a0 + l];
        }
    }
    __syncthreads();

    // ---- LN1 + embedding + leaky_relu : thread t -> agent t&63, 4 outputs ----
    {
        int a = tid & 63;
        int e0 = (tid >> 6) * 4;
        const float* r = row + a * 41;
        float sum = 0.f, sq = 0.f;
        for (int f = 0; f < IN_F; ++f) { float v = r[f]; sum += v; sq += v * v; }
        float m = sum * (1.f / IN_F);
        float var = sq * (1.f / IN_F) - m * m;
        float inv = rsqrtf(var + LN_EPS);
        float x0 = 0.f, x1 = 0.f, x2 = 0.f, x3 = 0.f;
        for (int f = 0; f < IN_F; ++f) {
            float v = (r[f] - m) * inv * cst[C_LN1G + f] + cst[C_LN1B + f];
            x0 += v * cst[C_EMBW + (e0 + 0) * IN_F + f];
            x1 += v * cst[C_EMBW + (e0 + 1) * IN_F + f];
            x2 += v * cst[C_EMBW + (e0 + 2) * IN_F + f];
            x3 += v * cst[C_EMBW + (e0 + 3) * IN_F + f];
        }
        xT[(e0 + 0) * 64 + a] = lrelu(x0 + cst[C_EMBB + e0 + 0]);
        xT[(e0 + 1) * 64 + a] = lrelu(x1 + cst[C_EMBB + e0 + 1]);
        xT[(e0 + 2) * 64 + a] = lrelu(x2 + cst[C_EMBB + e0 + 2]);
        xT[(e0 + 3) * 64 + a] = lrelu(x3 + cst[C_EMBB + e0 + 3]);
    }
    __syncthreads();

    // ---- gates GEMM: lane = agent, wave w handles gate elems k in [16w,16w+16)
    //      for all 4 gate types (i,f,g,o interleaved -> elementwise is wave-local).
    //      Weight loads are wave-uniform -> scalar loads. ----
    const int l = tid & 63;
    const int w = __builtin_amdgcn_readfirstlane(tid >> 6);
    float acc[64];
#pragma unroll
    for (int q = 0; q < 4; ++q)
#pragma unroll
        for (int m = 0; m < 16; ++m)
            acc[q * 16 + m] = bias[q * 64 + w * 16 + m];

    for (int k = 0; k < EDIM; ++k) {
        float xv = xT[k * 64 + l];
        const float* wr = WiT + k * 256 + w * 16;
#pragma unroll
        for (int q = 0; q < 4; ++q)
#pragma unroll
            for (int m = 0; m < 16; ++m)
                acc[q * 16 + m] += xv * wr[q * 64 + m];
    }
    for (int k = 0; k < HDIM; ++k) {
        float hv = hT[k * 64 + l];
        const float* wr = WhT + k * 256 + w * 16;
#pragma unroll
        for (int q = 0; q < 4; ++q)
#pragma unroll
            for (int m = 0; m < 16; ++m)
                acc[q * 16 + m] += hv * wr[q * 64 + m];
    }
    __syncthreads();   // all GEMM reads of hT done before h_new overwrites it

    // ---- LSTM cell elementwise (wave-local), write h/c transposed ----
    {
        int a = a0 + l;
#pragma unroll
        for (int m = 0; m < 16; ++m) {
            int k = w * 16 + m;
            float gi = acc[0 * 16 + m];
            float gf = acc[1 * 16 + m];
            float gg = acc[2 * 16 + m];
            float go = acc[3 * 16 + m];
            float c_old = c_ws[k * NAGENTS + a];
            float cn = fsigmoid(gf) * c_old + fsigmoid(gi) * ftanh(gg);
            float hn = fsigmoid(go) * ftanh(cn);
            c_ws[k * NAGENTS + a] = cn;
            h_ws[k * NAGENTS + a] = hn;
            hT[k * 64 + l] = hn;
        }
    }
    __syncthreads();

    // ---- LN2 + hidden2pos + write pred slab ----
    if (tid < 128) {
        int a = tid >> 1, d = tid & 1;
        float sum = 0.f, sq = 0.f;
        for (int k = 0; k < HDIM; ++k) { float v = hT[k * 64 + a]; sum += v; sq += v * v; }
        float m = sum * (1.f / HDIM);
        float var = sq * (1.f / HDIM) - m * m;
        float inv = rsqrtf(var + LN_EPS);
        float p = cst[C_H2PB + d];
        for (int k = 0; k < HDIM; ++k) {
            float v = (hT[k * 64 + a] - m) * inv * cst[C_LN2G + k] + cst[C_LN2B + k];
            p += v * cst[C_H2PW + d * 64 + k];
        }
        out[s * SLAB + a0 * 2 + tid] = p;
    }
}

extern "C" void kernel_launch(void* const* d_in, const int* in_sizes, int n_in,
                              void* d_out, int out_size, void* d_ws, size_t ws_size,
                              hipStream_t stream) {
    const float* traj  = (const float*)d_in[0];
    // d_in[1] = traj_rel (unused in use_rel_disp=False branch)
    const float* dec_h = (const float*)d_in[2];
    const float* W_ih  = (const float*)d_in[3];
    const float* W_hh  = (const float*)d_in[4];
    const float* b_ih  = (const float*)d_in[5];
    const float* b_hh  = (const float*)d_in[6];
    const float* emb_W = (const float*)d_in[7];
    const float* emb_b = (const float*)d_in[8];
    const float* h2p_W = (const float*)d_in[9];
    const float* h2p_b = (const float*)d_in[10];
    const float* ln1_g = (const float*)d_in[11];
    const float* ln1_b = (const float*)d_in[12];
    const float* ln2_g = (const float*)d_in[13];
    const float* ln2_b = (const float*)d_in[14];
    float* out = (float*)d_out;
    float* ws  = (float*)d_ws;

    init_kernel<<<4096, NTHREADS, 0, stream>>>(dec_h, W_ih, W_hh, b_ih, b_hh, ws);
    for (int s = 0; s < PRED; ++s) {
        step_kernel<<<NBLOCKS, NTHREADS, 0, stream>>>(
            s, traj, out, ws, emb_W, emb_b, h2p_W, h2p_b,
            ln1_g, ln1_b, ln2_g, ln2_b);
    }
}

// Round 4
// 701.739 us; speedup vs baseline: 1.6173x; 1.6173x over previous
//
#include <hip/hip_runtime.h>

#define NAGENTS 32768
#define SLAB    65536            // NAGENTS*2
#define SPLIT   1310720          // 20*SLAB : flat idx below -> traj_abs, above -> out
#define PRED    30
#define IN_F    40
#define LN_EPS  1e-5f
#define XSTRIDE 104              // shorts per agent row: 96 used (16 x + 64 h + 16 zero) + 8 pad

typedef short bf16x8 __attribute__((ext_vector_type(8)));
typedef short bf16x4 __attribute__((ext_vector_type(4)));
typedef float f32x4  __attribute__((ext_vector_type(4)));

// ---- ws layout (bytes) ----
// [0, 4MB)        : h state, bf16, [agent][64]
// [4MB, 12MB)     : c state, fp32, [agent][64]
// [12MB, +48KB)   : packed B-fragments, bf16, [tid][96]
#define WS_H_OFF  0
#define WS_C_OFF  (4u<<20)
#define WS_W_OFF  (12u<<20)

// cst float offsets
#define C_EMBW 0      // 640
#define C_EMBB 640    // 16
#define C_LN1G 656    // 40
#define C_LN1B 696    // 40
#define C_LN2G 736    // 64
#define C_LN2B 800    // 64
#define C_H2PW 864    // 128
#define C_H2PB 992    // 2
#define C_BIAS 994    // 256 (b_ih + b_hh)
#define C_TOT  1250

__device__ __forceinline__ float fsigmoid(float x){ return 1.f/(1.f+__expf(-x)); }
__device__ __forceinline__ float ftanh(float x){
    float t = __expf(-2.f*fabsf(x));
    float r = (1.f-t)/(1.f+t);
    return copysignf(r, x);
}
__device__ __forceinline__ float lrelu(float x){ return x > 0.f ? x : 0.01f*x; }
__device__ __forceinline__ short f2bf(float x){
    unsigned u = __float_as_uint(x);
    return (short)((u + 0x7FFFu + ((u>>16)&1u)) >> 16);   // RNE
}
__device__ __forceinline__ float bf2f(short s){
    return __uint_as_float(((unsigned)(unsigned short)s) << 16);
}

// ---- init: h0 (bf16), c0 (zero), packed weight fragments ----
__global__ void init_kernel(const float* __restrict__ dec_h,
                            const float* __restrict__ W_ih,
                            const float* __restrict__ W_hh,
                            char* __restrict__ ws)
{
    short* hws = (short*)(ws + WS_H_OFF);
    float* cws = (float*)(ws + WS_C_OFF);
    short* wpk = (short*)(ws + WS_W_OFF);

    int gtid = blockIdx.x * blockDim.x + threadIdx.x;
    const int N = NAGENTS * 64;  // 2M
    for (int i = gtid; i < N; i += gridDim.x * blockDim.x) {
        hws[i] = f2bf(dec_h[i]);   // dec_h flat is already [agent][k]
        cws[i] = 0.f;
    }
    // packed B fragments: idx = tid*96 + g*24 + ks*8 + j
    for (int idx = gtid; idx < 256*96; idx += gridDim.x * blockDim.x) {
        int tid = idx / 96, r = idx - tid*96;
        int g = r / 24, r2 = r - g*24;
        int ks = r2 >> 3, j = r2 & 7;
        int w = tid >> 6, l = tid & 63;
        int cl = l & 15, kb = l >> 4;
        int n = g*64 + w*16 + cl;
        int k = ks*32 + kb*8 + j;
        float f = 0.f;
        if (k < 16)      f = W_ih[n*16 + k];
        else if (k < 80) f = W_hh[n*64 + (k-16)];
        wpk[idx] = f2bf(f);
    }
}

__global__ __launch_bounds__(256, 2)
void step_kernel(int s,
                 const float* __restrict__ traj,
                 float* __restrict__ out,
                 char* __restrict__ ws,
                 const float* __restrict__ b_ih, const float* __restrict__ b_hh,
                 const float* __restrict__ emb_W, const float* __restrict__ emb_b,
                 const float* __restrict__ h2p_W, const float* __restrict__ h2p_b,
                 const float* __restrict__ ln1_g, const float* __restrict__ ln1_b,
                 const float* __restrict__ ln2_g, const float* __restrict__ ln2_b)
{
    __shared__ float row[64*41];        // LN1 input rows, padded
    __shared__ short Xs[64*XSTRIDE];    // bf16 A-operand [agent][k]: 0..16 x, 16..80 h, 80..96 zero
    __shared__ float cst[C_TOT];

    short* __restrict__ hws = (short*)(ws + WS_H_OFF);
    float* __restrict__ cws = (float*)(ws + WS_C_OFF);
    const short* __restrict__ wpk = (const short*)(ws + WS_W_OFF);

    const int tid = threadIdx.x;
    const int a0  = blockIdx.x * 64;
    const int l   = tid & 63;
    const int w   = __builtin_amdgcn_readfirstlane(tid >> 6);
    const int cl  = l & 15;
    const int kb  = l >> 4;
    const int nh  = w*16 + cl;          // gate-elem column this lane owns

    // ---- c loads first: no dependencies, overlap everything below ----
    float cs[4][4];
    float* cbase = cws + a0*64 + nh;
#pragma unroll
    for (int mt = 0; mt < 4; ++mt)
#pragma unroll
        for (int r = 0; r < 4; ++r)
            cs[mt][r] = cbase[(mt*16 + kb*4 + r)*64];

    // ---- B fragments: 6 contiguous 16B loads per lane (L2 broadcast) ----
    bf16x8 bw[4][3];
    {
        const bf16x8* wp = (const bf16x8*)(wpk + tid*96);
#pragma unroll
        for (int g = 0; g < 4; ++g)
#pragma unroll
            for (int ks = 0; ks < 3; ++ks)
                bw[g][ks] = wp[g*3 + ks];
    }

    // ---- stage small consts ----
    for (int i = tid; i < 640; i += 256) cst[C_EMBW+i] = emb_W[i];
    if (tid < 16)  cst[C_EMBB+tid] = emb_b[tid];
    if (tid < 40)  { cst[C_LN1G+tid] = ln1_g[tid]; cst[C_LN1B+tid] = ln1_b[tid]; }
    if (tid < 64)  { cst[C_LN2G+tid] = ln2_g[tid]; cst[C_LN2B+tid] = ln2_b[tid]; }
    if (tid < 128) cst[C_H2PW+tid] = h2p_W[tid];
    if (tid < 2)   cst[C_H2PB+tid] = h2p_b[tid];
    cst[C_BIAS+tid] = b_ih[tid] + b_hh[tid];

    // ---- stage LN1 rows: flat sliding window over [traj_abs ++ out] ----
    {
        const int Gb = s*SLAB + a0*IN_F;
        for (int g = tid; g < 64*IN_F; g += 256) {
            int G = Gb + g;
            float v = (G < SPLIT) ? traj[G] : out[G - SPLIT];
            int a = g / IN_F;
            int f = g - a*IN_F;
            row[a*41 + f] = v;
        }
    }
    // ---- stage h: global bf16 [a][64] -> Xs h-region (16B chunks) ----
    for (int i = tid; i < 512; i += 256) {
        int a = i >> 3, c8 = i & 7;
        *(bf16x8*)&Xs[a*XSTRIDE + 16 + c8*8] =
            *(const bf16x8*)&hws[(a0 + a)*64 + c8*8];
    }
    // ---- zero k-pad [80,96) ----
    for (int i = tid; i < 64*2; i += 256) {
        int a = i >> 1, c8 = 10 + (i & 1);
        *(bf16x8*)&Xs[a*XSTRIDE + c8*8] = bf16x8{0,0,0,0,0,0,0,0};
    }
    __syncthreads();

    // ---- LN1 + embedding + leaky_relu -> Xs[:,0:16) bf16 ----
    {
        int a  = tid & 63;
        int e0 = (tid >> 6) * 4;
        const float* r = row + a*41;
        float sum = 0.f, sq = 0.f;
        for (int f = 0; f < IN_F; ++f) { float v = r[f]; sum += v; sq += v*v; }
        float m   = sum * (1.f/IN_F);
        float var = sq * (1.f/IN_F) - m*m;
        float inv = rsqrtf(var + LN_EPS);
        float x0=0.f, x1=0.f, x2=0.f, x3=0.f;
        for (int f = 0; f < IN_F; ++f) {
            float v = (r[f]-m)*inv*cst[C_LN1G+f] + cst[C_LN1B+f];
            x0 += v * cst[C_EMBW + (e0+0)*IN_F + f];
            x1 += v * cst[C_EMBW + (e0+1)*IN_F + f];
            x2 += v * cst[C_EMBW + (e0+2)*IN_F + f];
            x3 += v * cst[C_EMBW + (e0+3)*IN_F + f];
        }
        bf16x4 xa;
        xa[0] = f2bf(lrelu(x0 + cst[C_EMBB+e0+0]));
        xa[1] = f2bf(lrelu(x1 + cst[C_EMBB+e0+1]));
        xa[2] = f2bf(lrelu(x2 + cst[C_EMBB+e0+2]));
        xa[3] = f2bf(lrelu(x3 + cst[C_EMBB+e0+3]));
        *(bf16x4*)&Xs[a*XSTRIDE + e0] = xa;   // 8B aligned
    }
    __syncthreads();

    // ---- gates GEMM via MFMA: D[agent][g*64+nh] ----
    // A: lane holds A[m=cl][k=kb*8+j]; B: lane holds B[k][n=cl] (pre-packed);
    // C/D: col=cl, row=kb*4+reg  (m89/m91-verified layouts)
    f32x4 acc[4][4];
#pragma unroll
    for (int g = 0; g < 4; ++g) {
        float bb = cst[C_BIAS + g*64 + nh];
#pragma unroll
        for (int mt = 0; mt < 4; ++mt) acc[mt][g] = f32x4{bb, bb, bb, bb};
    }
#pragma unroll
    for (int mt = 0; mt < 4; ++mt) {
        const short* base = &Xs[(mt*16 + cl)*XSTRIDE + kb*8];
        bf16x8 af0 = *(const bf16x8*)(base);        // k 0..31
        bf16x8 af1 = *(const bf16x8*)(base + 32);   // k 32..63
        bf16x8 af2 = *(const bf16x8*)(base + 64);   // k 64..95 (incl. zero pad)
#pragma unroll
        for (int g = 0; g < 4; ++g) {
            acc[mt][g] = __builtin_amdgcn_mfma_f32_16x16x32_bf16(af0, bw[g][0], acc[mt][g], 0, 0, 0);
            acc[mt][g] = __builtin_amdgcn_mfma_f32_16x16x32_bf16(af1, bw[g][1], acc[mt][g], 0, 0, 0);
            acc[mt][g] = __builtin_amdgcn_mfma_f32_16x16x32_bf16(af2, bw[g][2], acc[mt][g], 0, 0, 0);
        }
    }
    __syncthreads();   // all Xs reads done before h overwrite

    // ---- LSTM elementwise (lane-local); c -> global, h -> Xs ----
#pragma unroll
    for (int mt = 0; mt < 4; ++mt) {
        int abase = mt*16 + kb*4;
#pragma unroll
        for (int r = 0; r < 4; ++r) {
            float cn = fsigmoid(acc[mt][1][r]) * cs[mt][r]
                     + fsigmoid(acc[mt][0][r]) * ftanh(acc[mt][2][r]);
            float hn = fsigmoid(acc[mt][3][r]) * ftanh(cn);
            cbase[(abase + r)*64] = cn;
            Xs[(abase + r)*XSTRIDE + 16 + nh] = f2bf(hn);
        }
    }
    __syncthreads();

    // ---- h writeback (coalesced, all threads) ----
    for (int i = tid; i < 512; i += 256) {
        int a = i >> 3, c8 = i & 7;
        *(bf16x8*)&hws[(a0 + a)*64 + c8*8] =
            *(const bf16x8*)&Xs[a*XSTRIDE + 16 + c8*8];
    }

    // ---- LN2 + hidden2pos -> out slab s (tid<128) ----
    if (tid < 128) {
        int a = tid >> 1, d = tid & 1;
        const bf16x8* hp = (const bf16x8*)&Xs[a*XSTRIDE + 16];
        float sum = 0.f, sq = 0.f;
#pragma unroll
        for (int ch = 0; ch < 8; ++ch) {
            bf16x8 v = hp[ch];
#pragma unroll
            for (int j = 0; j < 8; ++j) { float f = bf2f(v[j]); sum += f; sq += f*f; }
        }
        float m   = sum * (1.f/64);
        float var = sq * (1.f/64) - m*m;
        float inv = rsqrtf(var + LN_EPS);
        float p = cst[C_H2PB + d];
#pragma unroll
        for (int ch = 0; ch < 8; ++ch) {
            bf16x8 v = hp[ch];
#pragma unroll
            for (int j = 0; j < 8; ++j) {
                int k = ch*8 + j;
                float f = bf2f(v[j]);
                p += ((f-m)*inv*cst[C_LN2G+k] + cst[C_LN2B+k]) * cst[C_H2PW + d*64 + k];
            }
        }
        out[s*SLAB + a0*2 + tid] = p;
    }
}

extern "C" void kernel_launch(void* const* d_in, const int* in_sizes, int n_in,
                              void* d_out, int out_size, void* d_ws, size_t ws_size,
                              hipStream_t stream) {
    const float* traj  = (const float*)d_in[0];
    // d_in[1] = traj_rel (unused)
    const float* dec_h = (const float*)d_in[2];
    const float* W_ih  = (const float*)d_in[3];
    const float* W_hh  = (const float*)d_in[4];
    const float* b_ih  = (const float*)d_in[5];
    const float* b_hh  = (const float*)d_in[6];
    const float* emb_W = (const float*)d_in[7];
    const float* emb_b = (const float*)d_in[8];
    const float* h2p_W = (const float*)d_in[9];
    const float* h2p_b = (const float*)d_in[10];
    const float* ln1_g = (const float*)d_in[11];
    const float* ln1_b = (const float*)d_in[12];
    const float* ln2_g = (const float*)d_in[13];
    const float* ln2_b = (const float*)d_in[14];
    float* out = (float*)d_out;
    char* ws   = (char*)d_ws;

    init_kernel<<<1024, 256, 0, stream>>>(dec_h, W_ih, W_hh, ws);
    for (int s = 0; s < PRED; ++s) {
        step_kernel<<<512, 256, 0, stream>>>(
            s, traj, out, ws, b_ih, b_hh, emb_W, emb_b, h2p_W, h2p_b,
            ln1_g, ln1_b, ln2_g, ln2_b);
    }
}